// Round 3
// baseline (71.602 us; speedup 1.0000x reference)
//
#include <hip/hip_runtime.h>

#define M_ROWS 65536
#define LENGTH 512
#define BLOCK 512
// each wave handles 1024 consecutive floats (= 2 rows); 8 waves/block
// total waves = 65536*512/1024 = 32768 -> 4096 blocks
#define NBLOCKS 4096

__device__ __forceinline__ void chunk_acc(float& acc, float4 v, float4 m, float p0) {
  float t;
  t = fabsf(v.x - p0) - 1.0f;  acc += fmaxf(t, 0.0f) * m.x;
  t = fabsf(v.y - v.x) - 1.0f; acc += fmaxf(t, 0.0f) * m.y;
  t = fabsf(v.z - v.y) - 1.0f; acc += fmaxf(t, 0.0f) * m.z;
  t = fabsf(v.w - v.z) - 1.0f; acc += fmaxf(t, 0.0f) * m.w;
}

__global__ __launch_bounds__(BLOCK) void connect_loss_fused(
    const float* __restrict__ x,
    const float* __restrict__ mask,
    float* __restrict__ out) {
  const int lane = threadIdx.x & 63;
  const int wave = threadIdx.x >> 6;
  const size_t wave_base = ((size_t)blockIdx.x * (BLOCK / 64) + wave) * 1024;

  const float4* xb = reinterpret_cast<const float4*>(x + wave_base);
  const float4* mb = reinterpret_cast<const float4*>(mask + wave_base);

  // Issue all 8 coalesced 1KB wave-loads up front (max MLP, single wait).
  float4 v0 = xb[lane];
  float4 v1 = xb[64 + lane];
  float4 v2 = xb[128 + lane];
  float4 v3 = xb[192 + lane];
  float4 m0 = mb[lane];
  float4 m1 = mb[64 + lane];
  float4 m2 = mb[128 + lane];
  float4 m3 = mb[192 + lane];

  float acc = 0.0f;

  // chunk 0: row floats [0,256); lane 0 is column 0 -> zero first diff
  {
    float p = __shfl_up(v0.w, 1);
    if (lane == 0) p = v0.x;
    chunk_acc(acc, v0, m0, p);
  }
  // chunk 1: floats [256,512); lane 0's prev is chunk0 lane63 .w
  {
    float p = __shfl_up(v1.w, 1);
    float last = __shfl(v0.w, 63);
    if (lane == 0) p = last;
    chunk_acc(acc, v1, m1, p);
  }
  // chunk 2: floats [512,768) = start of next row; zero first diff
  {
    float p = __shfl_up(v2.w, 1);
    if (lane == 0) p = v2.x;
    chunk_acc(acc, v2, m2, p);
  }
  // chunk 3: floats [768,1024); lane 0's prev is chunk2 lane63 .w
  {
    float p = __shfl_up(v3.w, 1);
    float last = __shfl(v2.w, 63);
    if (lane == 0) p = last;
    chunk_acc(acc, v3, m3, p);
  }

  // wave reduction (64 lanes)
#pragma unroll
  for (int off = 32; off; off >>= 1) acc += __shfl_down(acc, off);

  __shared__ float s[BLOCK / 64];
  if (lane == 0) s[wave] = acc;
  __syncthreads();
  if (threadIdx.x == 0) {
    float bs = 0.0f;
#pragma unroll
    for (int i = 0; i < BLOCK / 64; ++i) bs += s[i];
    atomicAdd(out, bs);  // d_out zeroed by memset node each call
  }
}

extern "C" void kernel_launch(void* const* d_in, const int* in_sizes, int n_in,
                              void* d_out, int out_size, void* d_ws, size_t ws_size,
                              hipStream_t stream) {
  const float* x = (const float*)d_in[0];
  const float* mask = (const float*)d_in[1];
  float* out = (float*)d_out;

  hipMemsetAsync(out, 0, sizeof(float), stream);
  connect_loss_fused<<<NBLOCKS, BLOCK, 0, stream>>>(x, mask, out);
}

// Round 4
// 44.708 us; speedup vs baseline: 1.6016x; 1.6016x over previous
//
#include <hip/hip_runtime.h>

#define M_ROWS 65536
#define LENGTH 512
#define NBLOCKS 2048
#define BLOCK 256

// One wave (64 lanes) per row; lane l covers columns [8l, 8l+8).
// Cross-lane previous element via shfl_up; column 0 contributes 0.
// Persistent grid: 2048 blocks x 4 waves, 8 rows per wave.
__global__ __launch_bounds__(BLOCK) void connect_loss_partial(
    const float* __restrict__ x,
    const float* __restrict__ mask,
    float* __restrict__ part) {
  const int wave = threadIdx.x >> 6;   // 0..3
  const int lane = threadIdx.x & 63;
  const int waves_total = gridDim.x * (BLOCK / 64);
  float acc = 0.0f;

  for (int row = blockIdx.x * (BLOCK / 64) + wave; row < M_ROWS; row += waves_total) {
    const float4* xr = reinterpret_cast<const float4*>(x + (size_t)row * LENGTH) + lane * 2;
    const float4* mr = reinterpret_cast<const float4*>(mask + (size_t)row * LENGTH) + lane * 2;
    float4 a0 = xr[0];
    float4 a1 = xr[1];
    float4 m0 = mr[0];
    float4 m1 = mr[1];

    // previous element for column 8l is column 8l-1 = lane (l-1)'s a1.w
    float prev = __shfl_up(a1.w, 1);

    float v[8] = {a0.x, a0.y, a0.z, a0.w, a1.x, a1.y, a1.z, a1.w};
    float m[8] = {m0.x, m0.y, m0.z, m0.w, m1.x, m1.y, m1.z, m1.w};

    // lane 0, column 0: diff defined as 0 (reference pads column 0 with zero)
    float p = (lane == 0) ? v[0] : prev;
#pragma unroll
    for (int c = 0; c < 8; ++c) {
      float d = v[c] - p;
      p = v[c];
      float t = fabsf(d) - 1.0f;
      acc += (t > 0.0f ? t : 0.0f) * m[c];
    }
  }

  // wave reduction (64 lanes)
#pragma unroll
  for (int off = 32; off; off >>= 1) acc += __shfl_down(acc, off);

  __shared__ float s[BLOCK / 64];
  if (lane == 0) s[wave] = acc;
  __syncthreads();
  if (threadIdx.x == 0) part[blockIdx.x] = s[0] + s[1] + s[2] + s[3];
}

// Single wave reads all 2048 partials (8 float4 per lane), reduces, writes out.
__global__ __launch_bounds__(64) void connect_loss_reduce(
    const float* __restrict__ part, float* __restrict__ out) {
  const int lane = threadIdx.x;
  const float4* p4 = reinterpret_cast<const float4*>(part);
  float acc = 0.0f;
#pragma unroll
  for (int i = 0; i < NBLOCKS / 4 / 64; ++i) {
    float4 v = p4[i * 64 + lane];
    acc += (v.x + v.y) + (v.z + v.w);
  }
#pragma unroll
  for (int off = 32; off; off >>= 1) acc += __shfl_down(acc, off);
  if (lane == 0) out[0] = acc;
}

extern "C" void kernel_launch(void* const* d_in, const int* in_sizes, int n_in,
                              void* d_out, int out_size, void* d_ws, size_t ws_size,
                              hipStream_t stream) {
  const float* x = (const float*)d_in[0];
  const float* mask = (const float*)d_in[1];
  float* out = (float*)d_out;
  float* part = (float*)d_ws;  // NBLOCKS floats

  connect_loss_partial<<<NBLOCKS, BLOCK, 0, stream>>>(x, mask, part);
  connect_loss_reduce<<<1, 64, 0, stream>>>(part, out);
}